// Round 2
// baseline (138.296 us; speedup 1.0000x reference)
//
#include <hip/hip_runtime.h>
#include <math.h>

#define EPS 1e-12f

typedef float f4 __attribute__((ext_vector_type(4)));

// ---------------------------------------------------------------------------
// Stage 1a: per-pixel sum-of-squares partials with 1 KB-contiguous wave loads.
//
// Old pattern: each wave read 256 B row-chunks at 16 KB stride -> ~2.5 TB/s
// (row-activate-bound). New: block = (tensor, b, row-tile, 64-ch split); each
// wave reads a full 1 KB channel-slab (4 rows t0 / 8 rows t1) contiguously.
// Geometry identical for both tensors: QUADS=64, CG=8 waves, CPT=8 channels,
// block reads 64ch x 1KB x 2 streams = 128 KB. 768 uniform blocks.
// Partials: t0 4/pixel, t1 8/pixel -> 1.5 MB total (+3% traffic).
// ---------------------------------------------------------------------------
template <int PLANE, int C, int CS_N>
__device__ __forceinline__ void partial_tile(
    const float* __restrict__ xo, const float* __restrict__ xg,
    float* __restrict__ part,   // [2][8][CS_N][PLANE]
    int b, int tile, int cs, int tid, float* lds /* 4096 floats */)
{
    constexpr int SLABF = 256;              // floats per channel-slab (1 KB)
    constexpr int CG    = 8;                // channel groups (one per wave)
    constexpr int CPT   = (C / CS_N) / CG;  // channels per thread = 8
    static_assert(CPT == 8, "geometry");

    const int quad = tid & 63;              // wave lanes cover 1 KB slab
    const int cg   = tid >> 6;              // wave id = channel group
    const int base = b * C * PLANE + tile * SLABF + quad * 4;
    const int c0   = cs * (C / CS_N) + cg * CPT;

    f4 so = {0.f, 0.f, 0.f, 0.f};
    f4 sg = {0.f, 0.f, 0.f, 0.f};
#pragma unroll
    for (int ib = 0; ib < CPT / 4; ++ib) {
        f4 vo[4], vg[4];
#pragma unroll
        for (int u = 0; u < 4; ++u) {
            const int off = base + (c0 + ib * 4 + u) * PLANE;
            vo[u] = __builtin_nontemporal_load(reinterpret_cast<const f4*>(xo + off));
            vg[u] = __builtin_nontemporal_load(reinterpret_cast<const f4*>(xg + off));
        }
#pragma unroll
        for (int u = 0; u < 4; ++u) {
            so += vo[u] * vo[u];
            sg += vg[u] * vg[u];
        }
    }

    // lds layout: [2 streams][CG][SLABF]
    *reinterpret_cast<f4*>(lds + (0 * CG + cg) * SLABF + quad * 4) = so;
    *reinterpret_cast<f4*>(lds + (1 * CG + cg) * SLABF + quad * 4) = sg;
    __syncthreads();

    // combine across the 8 channel groups; write 256 px x 2 streams partials
    if (tid < 128) {
        const int s = tid >> 6;
        const int q = tid & 63;
        f4 a = {0.f, 0.f, 0.f, 0.f};
#pragma unroll
        for (int g = 0; g < CG; ++g)
            a += *reinterpret_cast<const f4*>(lds + (s * CG + g) * SLABF + q * 4);
        *reinterpret_cast<f4*>(
            part + ((s * 8 + b) * CS_N + cs) * PLANE + tile * SLABF + q * 4) = a;
    }
}

__global__ __launch_bounds__(512) void stage1a_kernel(
    const float* __restrict__ o0, const float* __restrict__ g0,
    const float* __restrict__ o1, const float* __restrict__ g1,
    float* __restrict__ part0, float* __restrict__ part1,
    float* __restrict__ out)
{
    __shared__ float lds[4096];
    const int bid = blockIdx.x;
    if (bid == 0 && threadIdx.x == 0) out[0] = 0.0f;  // stage 2 atomicAdds
    if (bid < 512) {
        // t0: b(8) x tile(16: 4 rows) x cs(4: 64ch)
        const int b = bid >> 6, tile = (bid >> 2) & 15, cs = bid & 3;
        partial_tile<4096, 256, 4>(o0, g0, part0, b, tile, cs, threadIdx.x, lds);
    } else {
        // t1: b(8) x tile(4: 8 rows) x cs(8: 64ch)
        const int e = bid - 512;
        const int b = e >> 5, tile = (e >> 3) & 3, cs = e & 7;
        partial_tile<1024, 512, 8>(o1, g1, part1, b, tile, cs, threadIdx.x, lds);
    }
}

// ---------------------------------------------------------------------------
// Stage 2 (merged): per (tensor t, batch b, kernel k) block: combine channel-
// split partials -> p -> diff -> row k-window sums -> column k-window sums ->
// squared mean -> atomicAdd. Partials are 1.5 MB total (L2/L3-resident).
// ---------------------------------------------------------------------------
__global__ __launch_bounds__(256) void stage2_kernel(
    const float* __restrict__ part0, const float* __restrict__ part1,
    float* __restrict__ out)
{
    __shared__ float d[4096];            // diff plane (t0: 16 KB)
    __shared__ float rbuf[64 * 62];      // row-window sums [H][V]
    __shared__ float wsum[4];

    const int bid = blockIdx.x;          // [0, 48)
    const int t   = bid / 24;            // tensor 0/1
    const int rem = bid % 24;
    const int b   = rem / 3;
    const int ki  = rem % 3;
    const int k   = 3 + 2 * ki;          // 3, 5, 7
    const int H   = t ? 32 : 64;         // W == H
    const int V   = H - k + 1;
    const int PLANE = H * H;
    const int CS  = t ? 8 : 4;
    const float* pb = t ? part1 : part0;
    const int tid = threadIdx.x;

    const float* po = pb + (0 * 8 + b) * CS * PLANE;
    const float* pg = pb + (1 * 8 + b) * CS * PLANE;

    // per-pixel totals, then d = p_out - p_gt
    for (int q = tid; q < PLANE / 4; q += 256) {
        f4 ao = {0.f, 0.f, 0.f, 0.f};
        f4 ag = {0.f, 0.f, 0.f, 0.f};
        for (int c = 0; c < CS; ++c) {
            ao += *reinterpret_cast<const f4*>(po + c * PLANE + q * 4);
            ag += *reinterpret_cast<const f4*>(pg + c * PLANE + q * 4);
        }
        f4 dd;
#pragma unroll
        for (int j = 0; j < 4; ++j) {
            const float no = sqrtf(ao[j]);
            const float ng = sqrtf(ag[j]);
            dd[j] = ao[j] / fmaxf(no, EPS) - ag[j] / fmaxf(ng, EPS);
        }
        *reinterpret_cast<f4*>(d + q * 4) = dd;
    }
    __syncthreads();

    // row k-window sums -> rbuf[H][V] (packed stride V)
    for (int i = tid; i < H * V; i += 256) {
        const int y = i / V;
        const int x = i - y * V;
        float s = 0.f;
        for (int j = 0; j < k; ++j) s += d[y * H + x + j];
        rbuf[i] = s;
    }
    __syncthreads();

    // column k-window sums + squared accumulate
    float acc = 0.f;
    for (int i = tid; i < V * V; i += 256) {
        const int y = i / V;
        const int x = i - y * V;
        float s = 0.f;
        for (int j = 0; j < k; ++j) s += rbuf[(y + j) * V + x];
        acc = fmaf(s, s, acc);
    }

    // block reduction (wave64 shuffle, then LDS across 4 waves)
    for (int off = 32; off > 0; off >>= 1) acc += __shfl_down(acc, off);
    if ((tid & 63) == 0) wsum[tid >> 6] = acc;
    __syncthreads();
    if (tid == 0) {
        const float total = wsum[0] + wsum[1] + wsum[2] + wsum[3];
        atomicAdd(out, total / (float)(8 * V * V));  // mean over [B, V, V]
    }
}

extern "C" void kernel_launch(void* const* d_in, const int* in_sizes, int n_in,
                              void* d_out, int out_size, void* d_ws, size_t ws_size,
                              hipStream_t stream) {
    // setup_inputs order: out_feat0, out_feat1, gt_feat0, gt_feat1
    const float* out_feat0 = (const float*)d_in[0];  // [8, 256, 64, 64]
    const float* out_feat1 = (const float*)d_in[1];  // [8, 512, 32, 32]
    const float* gt_feat0  = (const float*)d_in[2];
    const float* gt_feat1  = (const float*)d_in[3];
    float* out = (float*)d_out;

    float* part0 = (float*)d_ws;                    // [2][8][4][4096] = 1 MB
    float* part1 = part0 + 2 * 8 * 4 * 4096;        // [2][8][8][1024] = 0.5 MB

    stage1a_kernel<<<768, 512, 0, stream>>>(
        out_feat0, gt_feat0, out_feat1, gt_feat1, part0, part1, out);
    stage2_kernel<<<48, 256, 0, stream>>>(part0, part1, out);
}

// Round 4
// 121.778 us; speedup vs baseline: 1.1356x; 1.1356x over previous
//
#include <hip/hip_runtime.h>
#include <math.h>

#define EPS 1e-12f

typedef float f4 __attribute__((ext_vector_type(4)));

// ---------------------------------------------------------------------------
// Stage 1a: per-pixel sum-of-squares partials, 1 KB-contiguous wave loads.
// Change vs R2: PLAIN float4 loads (drop __builtin_nontemporal_load) to match
// the m13-validated 6.29 TB/s streaming pattern. nt bypasses L2 and its read
// BW is unverified on gfx950; data is read-once so L2 pollution is moot.
//
// Block = (tensor, b, row-tile, 64-ch split); each wave reads full 1 KB
// channel-slabs. 768 uniform blocks x 512 threads (3 blocks/CU).
// Partials: [2 streams][8 b][CS_N][PLANE], 1.5 MB total (+3% traffic).
// ---------------------------------------------------------------------------
template <int PLANE, int C, int CS_N>
__device__ __forceinline__ void partial_tile(
    const float* __restrict__ xo, const float* __restrict__ xg,
    float* __restrict__ part,   // [2][8][CS_N][PLANE]
    int b, int tile, int cs, int tid, float* lds /* 4096 floats */)
{
    constexpr int SLABF = 256;              // floats per channel-slab (1 KB)
    constexpr int CG    = 8;                // channel groups (one per wave)
    constexpr int CPT   = (C / CS_N) / CG;  // channels per thread = 8
    static_assert(CPT == 8, "geometry");

    const int quad = tid & 63;              // wave lanes cover 1 KB slab
    const int cg   = tid >> 6;              // wave id = channel group
    const int base = b * C * PLANE + tile * SLABF + quad * 4;
    const int c0   = cs * (C / CS_N) + cg * CPT;

    f4 so = {0.f, 0.f, 0.f, 0.f};
    f4 sg = {0.f, 0.f, 0.f, 0.f};
#pragma unroll
    for (int ib = 0; ib < CPT / 4; ++ib) {
        f4 vo[4], vg[4];
#pragma unroll
        for (int u = 0; u < 4; ++u) {
            const int off = base + (c0 + ib * 4 + u) * PLANE;
            vo[u] = *reinterpret_cast<const f4*>(xo + off);
            vg[u] = *reinterpret_cast<const f4*>(xg + off);
        }
#pragma unroll
        for (int u = 0; u < 4; ++u) {
            so += vo[u] * vo[u];
            sg += vg[u] * vg[u];
        }
    }

    // lds layout: [2 streams][CG][SLABF]
    *reinterpret_cast<f4*>(lds + (0 * CG + cg) * SLABF + quad * 4) = so;
    *reinterpret_cast<f4*>(lds + (1 * CG + cg) * SLABF + quad * 4) = sg;
    __syncthreads();

    // combine across the 8 channel groups; write 256 px x 2 streams partials
    if (tid < 128) {
        const int s = tid >> 6;
        const int q = tid & 63;
        f4 a = {0.f, 0.f, 0.f, 0.f};
#pragma unroll
        for (int g = 0; g < CG; ++g)
            a += *reinterpret_cast<const f4*>(lds + (s * CG + g) * SLABF + q * 4);
        *reinterpret_cast<f4*>(
            part + ((s * 8 + b) * CS_N + cs) * PLANE + tile * SLABF + q * 4) = a;
    }
}

__global__ __launch_bounds__(512) void stage1a_kernel(
    const float* __restrict__ o0, const float* __restrict__ g0,
    const float* __restrict__ o1, const float* __restrict__ g1,
    float* __restrict__ part0, float* __restrict__ part1,
    float* __restrict__ out)
{
    __shared__ float lds[4096];
    const int bid = blockIdx.x;
    if (bid == 0 && threadIdx.x == 0) out[0] = 0.0f;  // stage 2 atomicAdds
    if (bid < 512) {
        // t0: b(8) x tile(16: 4 rows) x cs(4: 64ch)
        const int b = bid >> 6, tile = (bid >> 2) & 15, cs = bid & 3;
        partial_tile<4096, 256, 4>(o0, g0, part0, b, tile, cs, threadIdx.x, lds);
    } else {
        // t1: b(8) x tile(4: 8 rows) x cs(8: 64ch)
        const int e = bid - 512;
        const int b = e >> 5, tile = (e >> 3) & 3, cs = e & 7;
        partial_tile<1024, 512, 8>(o1, g1, part1, b, tile, cs, threadIdx.x, lds);
    }
}

// ---------------------------------------------------------------------------
// Stage 2 (templated): per (tensor t, batch b, kernel k) block: combine
// channel-split partials -> p -> diff -> row k-window -> col k-window ->
// squared mean -> atomicAdd. Compile-time (H, K, CS): divisions become
// magic-mul, window loops unroll. 512 threads (8 waves) halve serial depth.
// ---------------------------------------------------------------------------
template <int H, int K, int CS>
__device__ __forceinline__ void tile_mse(
    const float* __restrict__ po, const float* __restrict__ pg,
    float* __restrict__ out, int tid,
    float* d /* H*H */, float* rbuf /* H*(H-K+1) */, float* wsum /* 8 */)
{
    constexpr int V = H - K + 1;
    constexpr int PLANE = H * H;

    // per-pixel totals across CS splits, then d = p_out - p_gt
    for (int q = tid; q < PLANE / 4; q += 512) {
        f4 ao = {0.f, 0.f, 0.f, 0.f};
        f4 ag = {0.f, 0.f, 0.f, 0.f};
#pragma unroll
        for (int c = 0; c < CS; ++c) {
            ao += *reinterpret_cast<const f4*>(po + c * PLANE + q * 4);
            ag += *reinterpret_cast<const f4*>(pg + c * PLANE + q * 4);
        }
        f4 dd;
#pragma unroll
        for (int j = 0; j < 4; ++j) {
            const float no = sqrtf(ao[j]);
            const float ng = sqrtf(ag[j]);
            dd[j] = ao[j] / fmaxf(no, EPS) - ag[j] / fmaxf(ng, EPS);
        }
        *reinterpret_cast<f4*>(d + q * 4) = dd;
    }
    __syncthreads();

    // row K-window sums -> rbuf[H][V] (packed stride V)
    for (int i = tid; i < H * V; i += 512) {
        const int y = i / V;            // compile-time V -> magic-mul
        const int x = i - y * V;
        float s = 0.f;
#pragma unroll
        for (int j = 0; j < K; ++j) s += d[y * H + x + j];
        rbuf[i] = s;
    }
    __syncthreads();

    // column K-window sums + squared accumulate
    float acc = 0.f;
    for (int i = tid; i < V * V; i += 512) {
        const int y = i / V;
        const int x = i - y * V;
        float s = 0.f;
#pragma unroll
        for (int j = 0; j < K; ++j) s += rbuf[(y + j) * V + x];
        acc = fmaf(s, s, acc);
    }

    // block reduction (wave64 shuffle, then LDS across 8 waves)
    for (int off = 32; off > 0; off >>= 1) acc += __shfl_down(acc, off);
    if ((tid & 63) == 0) wsum[tid >> 6] = acc;
    __syncthreads();
    if (tid == 0) {
        float total = 0.f;
#pragma unroll
        for (int wv = 0; wv < 8; ++wv) total += wsum[wv];
        atomicAdd(out, total / (float)(8 * V * V));  // mean over [B, V, V]
    }
}

__global__ __launch_bounds__(512) void stage2_kernel(
    const float* __restrict__ part0, const float* __restrict__ part1,
    float* __restrict__ out)
{
    __shared__ float d[4096];            // diff plane (t0: 16 KB)
    __shared__ float rbuf[64 * 62];      // row-window sums [H][V]
    __shared__ float wsum[8];

    const int bid = blockIdx.x;          // [0, 48)
    const int t   = bid / 24;
    const int rem = bid % 24;
    const int b   = rem / 3;
    const int ki  = rem % 3;
    const int tid = threadIdx.x;

    if (t == 0) {
        const float* po = part0 + (0 * 8 + b) * 4 * 4096;
        const float* pg = part0 + (1 * 8 + b) * 4 * 4096;
        if      (ki == 0) tile_mse<64, 3, 4>(po, pg, out, tid, d, rbuf, wsum);
        else if (ki == 1) tile_mse<64, 5, 4>(po, pg, out, tid, d, rbuf, wsum);
        else              tile_mse<64, 7, 4>(po, pg, out, tid, d, rbuf, wsum);
    } else {
        const float* po = part1 + (0 * 8 + b) * 8 * 1024;
        const float* pg = part1 + (1 * 8 + b) * 8 * 1024;
        if      (ki == 0) tile_mse<32, 3, 8>(po, pg, out, tid, d, rbuf, wsum);
        else if (ki == 1) tile_mse<32, 5, 8>(po, pg, out, tid, d, rbuf, wsum);
        else              tile_mse<32, 7, 8>(po, pg, out, tid, d, rbuf, wsum);
    }
}

extern "C" void kernel_launch(void* const* d_in, const int* in_sizes, int n_in,
                              void* d_out, int out_size, void* d_ws, size_t ws_size,
                              hipStream_t stream) {
    // setup_inputs order: out_feat0, out_feat1, gt_feat0, gt_feat1
    const float* out_feat0 = (const float*)d_in[0];  // [8, 256, 64, 64]
    const float* out_feat1 = (const float*)d_in[1];  // [8, 512, 32, 32]
    const float* gt_feat0  = (const float*)d_in[2];
    const float* gt_feat1  = (const float*)d_in[3];
    float* out = (float*)d_out;

    float* part0 = (float*)d_ws;                    // [2][8][4][4096] = 1 MB
    float* part1 = part0 + 2 * 8 * 4 * 4096;        // [2][8][8][1024] = 0.5 MB

    stage1a_kernel<<<768, 512, 0, stream>>>(
        out_feat0, gt_feat0, out_feat1, gt_feat1, part0, part1, out);
    stage2_kernel<<<48, 512, 0, stream>>>(part0, part1, out);
}